// Round 2
// baseline (548.673 us; speedup 1.0000x reference)
//
#include <hip/hip_runtime.h>
#include <math.h>

#define Dm 1024
#define Hh 16
#define DHh 64
#define Bb 2
#define Nn 2048
#define Rr 4096
#define SCALE_ 0.125f
#define EPS_ 1e-5f
#define SMAX_ 4.0f
#define LOG2E_ 1.4426950408889634f

typedef unsigned short u16;
typedef __attribute__((ext_vector_type(8))) short short8;
typedef __attribute__((ext_vector_type(4))) float f32x4;

__device__ __forceinline__ u16 f2bf(float f) {
  union { float f; unsigned u; } v; v.f = f;
  unsigned r = v.u + 0x7fffu + ((v.u >> 16) & 1u);
  return (u16)(r >> 16);
}
__device__ __forceinline__ float bf2f(u16 h) {
  union { unsigned u; float f; } v; v.u = ((unsigned)h) << 16;
  return v.f;
}
// pack two floats -> two truncated bf16 in one u32 (lo=a, hi=b)
__device__ __forceinline__ unsigned pk2(float a, float b) {
  union { float f; unsigned u; } x, y; x.f = a; y.f = b;
  return (x.u >> 16) | (y.u & 0xffff0000u);
}

__device__ __forceinline__ void g2l16(const u16* g, const u16* l) {
  __builtin_amdgcn_global_load_lds(
      (const __attribute__((address_space(1))) void*)g,
      (__attribute__((address_space(3))) void*)l, 16, 0, 0);
}

// ---------------- all 4 weight transposes fp32 [K,N] -> bf16 [N,K], one kernel ----
__global__ void transpose_all(const float* __restrict__ qkv_w, const float* __restrict__ out_w,
                              const float* __restrict__ ff1_w, const float* __restrict__ ff2_w,
                              u16* __restrict__ qkvT, u16* __restrict__ outT,
                              u16* __restrict__ ff1T, u16* __restrict__ ff2T) {
  __shared__ float tile[32][33];
  int flat = blockIdx.x;
  const float* W; u16* WT; int K, N, local;
  if (flat < 3072)        { W = qkv_w; WT = qkvT; K = 1024; N = 3072; local = flat; }
  else if (flat < 4096)   { W = out_w; WT = outT; K = 1024; N = 1024; local = flat - 3072; }
  else if (flat < 8192)   { W = ff1_w; WT = ff1T; K = 1024; N = 4096; local = flat - 4096; }
  else                    { W = ff2_w; WT = ff2T; K = 4096; N = 1024; local = flat - 8192; }
  int nx = N / 32;
  int n0 = (local % nx) * 32, k0 = (local / nx) * 32;
  int tx = threadIdx.x, ty = threadIdx.y;  // 32 x 8
#pragma unroll
  for (int i = 0; i < 4; i++)
    tile[ty + 8 * i][tx] = W[(size_t)(k0 + ty + 8 * i) * N + n0 + tx];
  __syncthreads();
#pragma unroll
  for (int i = 0; i < 4; i++)
    WT[(size_t)(n0 + ty + 8 * i) * K + k0 + tx] = f2bf(tile[tx][ty + 8 * i]);
}

// ---------------- biasL16 = bf16(LOG2E*(sb*adj + mask) - SMAX*LOG2E) ----------------
__global__ void bias_precompute(const float* __restrict__ adj, const float* __restrict__ mask,
                                const float* __restrict__ sbp, u16* __restrict__ bias16) {
  const float sb = sbp[0];
  const float C3 = -SMAX_ * LOG2E_;
  size_t i = ((size_t)blockIdx.x * 256 + threadIdx.x) * 8;
  float4 a0 = *(const float4*)(adj + i);
  float4 a1 = *(const float4*)(adj + i + 4);
  float4 m0 = *(const float4*)(mask + i);
  float4 m1 = *(const float4*)(mask + i + 4);
  ushort4 o0, o1;
  o0.x = f2bf(fmaf(fmaf(sb, a0.x, m0.x), LOG2E_, C3));
  o0.y = f2bf(fmaf(fmaf(sb, a0.y, m0.y), LOG2E_, C3));
  o0.z = f2bf(fmaf(fmaf(sb, a0.z, m0.z), LOG2E_, C3));
  o0.w = f2bf(fmaf(fmaf(sb, a0.w, m0.w), LOG2E_, C3));
  o1.x = f2bf(fmaf(fmaf(sb, a1.x, m1.x), LOG2E_, C3));
  o1.y = f2bf(fmaf(fmaf(sb, a1.y, m1.y), LOG2E_, C3));
  o1.z = f2bf(fmaf(fmaf(sb, a1.z, m1.z), LOG2E_, C3));
  o1.w = f2bf(fmaf(fmaf(sb, a1.w, m1.w), LOG2E_, C3));
  *(ushort4*)(bias16 + i) = o0;
  *(ushort4*)(bias16 + i + 4) = o1;
}

// ---------------- layernorm [R,D] -> bf16; input fp32 (BI=0) or bf16 (BI=1) -------
template <int BI>
__global__ void ln_kernel(const void* __restrict__ xin, const float* __restrict__ g,
                          const float* __restrict__ be, u16* __restrict__ out) {
  int row = blockIdx.x;
  int t = threadIdx.x;  // 256
  float4 v;
  if (BI) {
    ushort4 uv = ((const ushort4*)((const u16*)xin + (size_t)row * Dm))[t];
    v.x = bf2f(uv.x); v.y = bf2f(uv.y); v.z = bf2f(uv.z); v.w = bf2f(uv.w);
  } else {
    v = ((const float4*)((const float*)xin + (size_t)row * Dm))[t];
  }
  float s = v.x + v.y + v.z + v.w;
  float s2 = v.x * v.x + v.y * v.y + v.z * v.z + v.w * v.w;
#pragma unroll
  for (int o = 32; o > 0; o >>= 1) { s += __shfl_down(s, o); s2 += __shfl_down(s2, o); }
  __shared__ float sm[8];
  int w = t >> 6;
  if ((t & 63) == 0) { sm[w] = s; sm[4 + w] = s2; }
  __syncthreads();
  if (t == 0) {
    float a = sm[0] + sm[1] + sm[2] + sm[3];
    float a2 = sm[4] + sm[5] + sm[6] + sm[7];
    float mu = a * (1.f / Dm);
    sm[0] = mu;
    sm[1] = rsqrtf(a2 * (1.f / Dm) - mu * mu + EPS_);
  }
  __syncthreads();
  float mu = sm[0], rstd = sm[1];
  float4 gv = ((const float4*)g)[t];
  float4 bv = ((const float4*)be)[t];
  ushort4 o4;
  o4.x = f2bf((v.x - mu) * rstd * gv.x + bv.x);
  o4.y = f2bf((v.y - mu) * rstd * gv.y + bv.y);
  o4.z = f2bf((v.z - mu) * rstd * gv.z + bv.z);
  o4.w = f2bf((v.w - mu) * rstd * gv.w + bv.w);
  ((ushort4*)(out + (size_t)row * Dm))[t] = o4;
}

// ---------------- bf16 GEMM, double-buffered + XCD m-strip ownership --------------
template <int MODE, int MI, int NI>
__global__ __launch_bounds__(256) void gemm_bt(
    const u16* __restrict__ A, const u16* __restrict__ BT,
    const float* __restrict__ bias, const void* __restrict__ res,
    void* __restrict__ Cout, u16* __restrict__ qb,
    u16* __restrict__ kb, u16* __restrict__ vb, int Ndim, int Kdim) {
  constexpr int TM = MI * 32, TN = NI * 32;
  constexpr int NS = (TM + TN) / 16;  // 16-row staging instrs per k-tile
  __shared__ u16 As[2][TM * 32];
  __shared__ u16 Bs[2][TN * 32];
  const int t = threadIdx.x;
  const int wave = t >> 6, lane = t & 63;
  const int wm = wave >> 1, wn = wave & 1;
  const int lr = lane & 15, lq = lane >> 4;
  const int flat = blockIdx.x + gridDim.x * blockIdx.y;
  constexpr int nMb = 4096 / TM;
  constexpr int mpx = nMb / 8;  // m-blocks per XCD
  const int xcd = flat & 7;
  const int p = flat >> 3;
  const int m0 = (xcd * mpx + (p % mpx)) * TM;
  const int n0 = (p / mpx) * TN;

  auto stage = [&](int kt, int bsel) {
#pragma unroll
    for (int s = wave; s < NS; s += 4) {
      if (s < TM / 16)
        g2l16(A + (size_t)(m0 + s * 16 + (lane >> 2)) * Kdim + kt + (lane & 3) * 8,
              &As[bsel][(s * 16) * 32]);
      else
        g2l16(BT + (size_t)(n0 + (s - TM / 16) * 16 + (lane >> 2)) * Kdim + kt + (lane & 3) * 8,
              &Bs[bsel][((s - TM / 16) * 16) * 32]);
    }
  };

  f32x4 acc[MI][NI];
#pragma unroll
  for (int i = 0; i < MI; i++)
#pragma unroll
    for (int j = 0; j < NI; j++) acc[i][j] = (f32x4){0.f, 0.f, 0.f, 0.f};

  stage(0, 0);
  int cur = 0;
  for (int kt = 0; kt < Kdim; kt += 32) {
    __syncthreads();  // vmcnt drain -> buf[cur] ready; protects buf[cur^1]
    if (kt + 32 < Kdim) stage(kt + 32, cur ^ 1);
    short8 af[MI], bf[NI];
#pragma unroll
    for (int i = 0; i < MI; i++)
      af[i] = *(const short8*)&As[cur][(wm * (MI * 16) + i * 16 + lr) * 32 + lq * 8];
#pragma unroll
    for (int j = 0; j < NI; j++)
      bf[j] = *(const short8*)&Bs[cur][(wn * (NI * 16) + j * 16 + lr) * 32 + lq * 8];
#pragma unroll
    for (int i = 0; i < MI; i++)
#pragma unroll
      for (int j = 0; j < NI; j++)
        acc[i][j] = __builtin_amdgcn_mfma_f32_16x16x32_bf16(af[i], bf[j], acc[i][j], 0, 0, 0);
    cur ^= 1;
  }

#pragma unroll
  for (int i = 0; i < MI; i++) {
#pragma unroll
    for (int j = 0; j < NI; j++) {
#pragma unroll
      for (int r = 0; r < 4; r++) {
        int row = m0 + wm * (MI * 16) + i * 16 + lq * 4 + r;
        int col = n0 + wn * (NI * 16) + j * 16 + lr;
        float val = acc[i][j][r] + bias[col];
        if (MODE == 0) {
          int s = col >> 10, rem = col & 1023;
          int hh = rem >> 6, dh = rem & 63;
          int bi = row >> 11, ni = row & 2047;
          if (s == 2) {
            vb[(((size_t)bi * Hh + hh) * DHh + dh) * Nn + ni] = f2bf(val);
          } else {
            u16* dst = (s == 0) ? qb : kb;
            dst[(((size_t)bi * Hh + hh) * Nn + ni) * DHh + dh] = f2bf(val);
          }
        } else if (MODE == 1) {
          size_t o = (size_t)row * Ndim + col;
          ((u16*)Cout)[o] = f2bf(val + ((const float*)res)[o]);
        } else if (MODE == 3) {
          size_t o = (size_t)row * Ndim + col;
          ((float*)Cout)[o] = val + bf2f(((const u16*)res)[o]);
        } else {
          // gelu(u) = u * sigmoid(1.5957691(u + 0.044715 u^3)); NaN-safe tails
          float u = val;
          float y2 = 1.5957691216f * fmaf(0.044715f * u, u * u, u);
          float gv = u / (1.f + __expf(-y2));
          size_t o = (size_t)row * Ndim + col;
          ((u16*)Cout)[o] = f2bf(gv);
        }
      }
    }
  }
}

// ---------------- flash attention v8: barrier-free, K/V direct from global -------
// grid (16, 32, 2): x=q-tile, y=head-batch, z=K-half.
// K/V per-iter tiles (8KB each) are L1/L2-resident (head K/V = 256KB, L3 backs all
// 16MB) -> no LDS staging, no __syncthreads at all. Only LDS use: per-wave-private
// P transpose bounce (18.4KB). Swapped QK^T (S^T) keeps bias loads ushort4 and
// P-writes packed b64. QK processed per-ns to cap VGPR pressure.
// Fixed max => partials combine exactly: O=(O0+O1)/(l0+l1).
__global__ __launch_bounds__(256) void attn_kernel(
    const u16* __restrict__ q, const u16* __restrict__ k, const u16* __restrict__ vT,
    const u16* __restrict__ bias16, u16* __restrict__ pO0, u16* __restrict__ pO1,
    float* __restrict__ pl) {
  const int qt = blockIdx.x, hb = blockIdx.y, kp = blockIdx.z;
  const int hh = hb & 15, b = hb >> 4;
  const int t = threadIdx.x, wave = t >> 6, lane = t & 63;
  const int lr = lane & 15, lq = lane >> 4;
  const size_t head_off = (((size_t)b * Hh + hh) * Nn) * DHh;
  const u16* Q = q + head_off;
  const u16* K = k + head_off;
  const u16* Vt = vT + head_off;  // [DH][N]
  const int q0 = qt * 128;
  const int kbase = kp * (Nn / 2);
  u16* pO = kp ? pO1 : pO0;

  __shared__ u16 Ps[4][32 * 72];  // per-wave private P bounce (only LDS use)

  short8 qf[2][2];
#pragma unroll
  for (int qs = 0; qs < 2; qs++) {
    const u16* Qr = Q + (size_t)(q0 + wave * 32 + qs * 16 + lr) * DHh;
    qf[qs][0] = *(const short8*)(Qr + lq * 8);
    qf[qs][1] = *(const short8*)(Qr + 32 + lq * 8);
  }
  f32x4 o_acc[2][4];
  float l_acc[2];
#pragma unroll
  for (int qs = 0; qs < 2; qs++) {
#pragma unroll
    for (int j = 0; j < 4; j++) o_acc[qs][j] = (f32x4){0.f, 0.f, 0.f, 0.f};
    l_acc[qs] = 0.f;
  }

  const int rsw = ((lr >> 2) & 3) << 4;
  // bias row for this thread's q (q = q0 + wave*32 + qs*16 + lr)
  const u16* bp = bias16 + ((size_t)b * Nn + q0 + wave * 32 + lr) * Nn;
  const float C1 = SCALE_ * LOG2E_;
  const int kend = kbase + Nn / 2;

#pragma unroll 2
  for (int kt = kbase; kt < kend; kt += 64) {
    // bias for this k-tile: [qs][ns] = bias(q=.., k = kt + ns*16 + lq*4 .. +3)
    ushort4 bw[2][4];
#pragma unroll
    for (int qs = 0; qs < 2; qs++)
#pragma unroll
      for (int ns = 0; ns < 4; ns++)
        bw[qs][ns] = *(const ushort4*)(bp + (size_t)qs * 16 * Nn + kt + ns * 16 + lq * 4);

    // QK^T swapped, per-ns: load K frags direct from global, 4 MFMA, exp, pack, store
#pragma unroll
    for (int ns = 0; ns < 4; ns++) {
      const u16* Kr = K + (size_t)(kt + ns * 16 + lr) * DHh + lq * 8;
      short8 k0 = *(const short8*)Kr;
      short8 k1 = *(const short8*)(Kr + 32);
      f32x4 z = (f32x4){0.f, 0.f, 0.f, 0.f};
      f32x4 s0 = __builtin_amdgcn_mfma_f32_16x16x32_bf16(k0, qf[0][0], z, 0, 0, 0);
      s0 = __builtin_amdgcn_mfma_f32_16x16x32_bf16(k1, qf[0][1], s0, 0, 0, 0);
      f32x4 s1 = __builtin_amdgcn_mfma_f32_16x16x32_bf16(k0, qf[1][0], z, 0, 0, 0);
      s1 = __builtin_amdgcn_mfma_f32_16x16x32_bf16(k1, qf[1][1], s1, 0, 0, 0);
      float p00 = exp2f(fmaf(s0[0], C1, bf2f(bw[0][ns].x)));
      float p01 = exp2f(fmaf(s0[1], C1, bf2f(bw[0][ns].y)));
      float p02 = exp2f(fmaf(s0[2], C1, bf2f(bw[0][ns].z)));
      float p03 = exp2f(fmaf(s0[3], C1, bf2f(bw[0][ns].w)));
      float p10 = exp2f(fmaf(s1[0], C1, bf2f(bw[1][ns].x)));
      float p11 = exp2f(fmaf(s1[1], C1, bf2f(bw[1][ns].y)));
      float p12 = exp2f(fmaf(s1[2], C1, bf2f(bw[1][ns].z)));
      float p13 = exp2f(fmaf(s1[3], C1, bf2f(bw[1][ns].w)));
      l_acc[0] += (p00 + p01) + (p02 + p03);
      l_acc[1] += (p10 + p11) + (p12 + p13);
      // stored col = true ^ (((row>>2)&3)<<4); row=qs*16+lr -> swz key (lr>>2)&3
      int sc = ((ns ^ ((lr >> 2) & 3)) << 4) + lq * 4;
      uint2 w0, w1;
      w0.x = pk2(p00, p01); w0.y = pk2(p02, p03);
      w1.x = pk2(p10, p11); w1.y = pk2(p12, p13);
      *(uint2*)&Ps[wave][lr * 72 + sc] = w0;
      *(uint2*)&Ps[wave][(16 + lr) * 72 + sc] = w1;
    }
    // P fragments back (wave-private; compiler orders ds_write->ds_read via lgkmcnt)
    short8 pf[2][2];
#pragma unroll
    for (int qs = 0; qs < 2; qs++) {
      pf[qs][0] = *(const short8*)&Ps[wave][(qs * 16 + lr) * 72 + ((lq * 8) ^ rsw)];
      pf[qs][1] = *(const short8*)&Ps[wave][(qs * 16 + lr) * 72 + ((32 + lq * 8) ^ rsw)];
    }
    // PV: V frags direct from global (vT[dh][n], contiguous in n)
#pragma unroll
    for (int j = 0; j < 4; j++) {
      const u16* Vr = Vt + (size_t)(j * 16 + lr) * Nn + kt + lq * 8;
      short8 vf0 = *(const short8*)Vr;
      short8 vf1 = *(const short8*)(Vr + 32);
      o_acc[0][j] = __builtin_amdgcn_mfma_f32_16x16x32_bf16(pf[0][0], vf0, o_acc[0][j], 0, 0, 0);
      o_acc[0][j] = __builtin_amdgcn_mfma_f32_16x16x32_bf16(pf[0][1], vf1, o_acc[0][j], 0, 0, 0);
      o_acc[1][j] = __builtin_amdgcn_mfma_f32_16x16x32_bf16(pf[1][0], vf0, o_acc[1][j], 0, 0, 0);
      o_acc[1][j] = __builtin_amdgcn_mfma_f32_16x16x32_bf16(pf[1][1], vf1, o_acc[1][j], 0, 0, 0);
    }
  }
  // epilogue: l per thread covers q=lr only -> reduce across the 4 lq groups
#pragma unroll
  for (int qs = 0; qs < 2; qs++) {
    float l = l_acc[qs];
    l += __shfl_xor(l, 16);
    l += __shfl_xor(l, 32);
    if (lane < 16)
      pl[((size_t)(kp * Bb + b) * Hh + hh) * Nn + q0 + wave * 32 + qs * 16 + lr] = l;
#pragma unroll
    for (int r = 0; r < 4; r++) {
      int qrow = q0 + wave * 32 + qs * 16 + lq * 4 + r;
#pragma unroll
      for (int j = 0; j < 4; j++) {
        pO[((size_t)(b * Nn + qrow)) * Dm + hh * DHh + j * 16 + lr] =
            f2bf(o_acc[qs][j][r]);
      }
    }
  }
}

// ---------------- combine K-split partials: ao = (O0+O1)/(l0+l1) ----------------
__global__ void attn_combine(const u16* __restrict__ pO0, const u16* __restrict__ pO1,
                             const float* __restrict__ pl, u16* __restrict__ ao) {
  int row = blockIdx.x;   // 0..4095
  int t = threadIdx.x;    // 256
  int col = t * 4;
  int b = row >> 11, n = row & 2047, hh = col >> 6;
  size_t li = ((size_t)b * Hh + hh) * Nn + n;
  float inv = 1.f / (pl[li] + pl[(size_t)Bb * Hh * Nn + li]);
  ushort4 a0 = *(const ushort4*)(pO0 + (size_t)row * Dm + col);
  ushort4 a1 = *(const ushort4*)(pO1 + (size_t)row * Dm + col);
  ushort4 o;
  o.x = f2bf((bf2f(a0.x) + bf2f(a1.x)) * inv);
  o.y = f2bf((bf2f(a0.y) + bf2f(a1.y)) * inv);
  o.z = f2bf((bf2f(a0.z) + bf2f(a1.z)) * inv);
  o.w = f2bf((bf2f(a0.w) + bf2f(a1.w)) * inv);
  *(ushort4*)(ao + (size_t)row * Dm + col) = o;
}

extern "C" void kernel_launch(void* const* d_in, const int* in_sizes, int n_in,
                              void* d_out, int out_size, void* d_ws, size_t ws_size,
                              hipStream_t stream) {
  const float* x     = (const float*)d_in[0];
  const float* adj   = (const float*)d_in[1];
  const float* amask = (const float*)d_in[2];
  const float* qkv_w = (const float*)d_in[3];
  const float* qkv_b = (const float*)d_in[4];
  const float* out_w = (const float*)d_in[5];
  const float* out_b = (const float*)d_in[6];
  const float* ln1_g = (const float*)d_in[7];
  const float* ln1_b = (const float*)d_in[8];
  const float* ln2_g = (const float*)d_in[9];
  const float* ln2_b = (const float*)d_in[10];
  const float* ff1_w = (const float*)d_in[11];
  const float* ff1_b = (const float*)d_in[12];
  const float* ff2_w = (const float*)d_in[13];
  const float* ff2_b = (const float*)d_in[14];
  const float* sbias = (const float*)d_in[15];

  char* w = (char*)d_ws;
  const size_t MB = 1024 * 1024;
  u16* h      = (u16*)(w);             // 8 MB
  u16* qb     = (u16*)(w + 8 * MB);    // 8 MB
  u16* kb     = (u16*)(w + 16 * MB);   // 8 MB
  u16* vb     = (u16*)(w + 24 * MB);   // 8 MB ([B,H,DH,N])
  u16* ao     = (u16*)(w + 32 * MB);   // 8 MB
  float* pl   = (float*)(w + 40 * MB); // 0.5 MB (dead before x1 write)
  u16* x1     = (u16*)(w + 40 * MB);   // 8 MB (bf16, written after combine)
  u16* pO0    = (u16*)(w + 48 * MB);   // 8 MB
  u16* pO1    = h;                     // 8 MB (h dead during attn)
  u16* qkvT   = (u16*)(w + 56 * MB);   // 6 MB
  u16* outT   = (u16*)(w + 62 * MB);   // 2 MB
  u16* ff1T   = (u16*)(w + 64 * MB);   // 8 MB
  u16* ff2T   = (u16*)(w + 72 * MB);   // 8 MB
  u16* bias16 = (u16*)(w + 80 * MB);   // 16.8 MB
  u16* ffo    = qb;                    // 32 MB alias over qb..ao (dead after out-proj)

  transpose_all<<<dim3(12288), dim3(32, 8), 0, stream>>>(
      qkv_w, out_w, ff1_w, ff2_w, qkvT, outT, ff1T, ff2T);

  bias_precompute<<<dim3((Bb * Nn * Nn) / (8 * 256)), dim3(256), 0, stream>>>(adj, amask, sbias, bias16);

  ln_kernel<0><<<dim3(Rr), dim3(256), 0, stream>>>(x, ln1_g, ln1_b, h);

  gemm_bt<0, 4, 4><<<dim3(3072 / 128, 4096 / 128), dim3(256), 0, stream>>>(
      h, qkvT, qkv_b, nullptr, nullptr, qb, kb, vb, 3072, 1024);

  attn_kernel<<<dim3(16, 32, 2), dim3(256), 0, stream>>>(qb, kb, vb, bias16, pO0, pO1, pl);

  attn_combine<<<dim3(Rr), dim3(256), 0, stream>>>(pO0, pO1, pl, ao);

  gemm_bt<1, 4, 2><<<dim3(1024 / 64, 4096 / 128), dim3(256), 0, stream>>>(
      ao, outT, out_b, x, (void*)x1, nullptr, nullptr, nullptr, 1024, 1024);

  ln_kernel<1><<<dim3(Rr), dim3(256), 0, stream>>>(x1, ln2_g, ln2_b, h);

  gemm_bt<2, 4, 4><<<dim3(4096 / 128, 4096 / 128), dim3(256), 0, stream>>>(
      h, ff1T, ff1_b, nullptr, (void*)ffo, nullptr, nullptr, nullptr, 4096, 1024);

  gemm_bt<3, 4, 2><<<dim3(1024 / 64, 4096 / 128), dim3(256), 0, stream>>>(
      ffo, ff2T, ff2_b, x1, d_out, nullptr, nullptr, nullptr, 1024, 4096);
}

// Round 4
// 451.951 us; speedup vs baseline: 1.2140x; 1.2140x over previous
//
#include <hip/hip_runtime.h>
#include <math.h>

#define Dm 1024
#define Hh 16
#define DHh 64
#define Bb 2
#define Nn 2048
#define Rr 4096
#define SCALE_ 0.125f
#define EPS_ 1e-5f
#define SMAX_ 4.0f
#define LOG2E_ 1.4426950408889634f

typedef unsigned short u16;
typedef __attribute__((ext_vector_type(8))) short short8;
typedef __attribute__((ext_vector_type(4))) float f32x4;

__device__ __forceinline__ u16 f2bf(float f) {
  union { float f; unsigned u; } v; v.f = f;
  unsigned r = v.u + 0x7fffu + ((v.u >> 16) & 1u);
  return (u16)(r >> 16);
}
__device__ __forceinline__ float bf2f(u16 h) {
  union { unsigned u; float f; } v; v.u = ((unsigned)h) << 16;
  return v.f;
}
// pack two floats -> two truncated bf16 in one u32 (lo=a, hi=b)
__device__ __forceinline__ unsigned pk2(float a, float b) {
  union { float f; unsigned u; } x, y; x.f = a; y.f = b;
  return (x.u >> 16) | (y.u & 0xffff0000u);
}

__device__ __forceinline__ void g2l16(const u16* g, const u16* l) {
  __builtin_amdgcn_global_load_lds(
      (const __attribute__((address_space(1))) void*)g,
      (__attribute__((address_space(3))) void*)l, 16, 0, 0);
}

// ---------------- all 4 weight transposes fp32 [K,N] -> bf16 [N,K], one kernel ----
__global__ void transpose_all(const float* __restrict__ qkv_w, const float* __restrict__ out_w,
                              const float* __restrict__ ff1_w, const float* __restrict__ ff2_w,
                              u16* __restrict__ qkvT, u16* __restrict__ outT,
                              u16* __restrict__ ff1T, u16* __restrict__ ff2T) {
  __shared__ float tile[32][33];
  int flat = blockIdx.x;
  const float* W; u16* WT; int K, N, local;
  if (flat < 3072)        { W = qkv_w; WT = qkvT; K = 1024; N = 3072; local = flat; }
  else if (flat < 4096)   { W = out_w; WT = outT; K = 1024; N = 1024; local = flat - 3072; }
  else if (flat < 8192)   { W = ff1_w; WT = ff1T; K = 1024; N = 4096; local = flat - 4096; }
  else                    { W = ff2_w; WT = ff2T; K = 4096; N = 1024; local = flat - 8192; }
  int nx = N / 32;
  int n0 = (local % nx) * 32, k0 = (local / nx) * 32;
  int tx = threadIdx.x, ty = threadIdx.y;  // 32 x 8
#pragma unroll
  for (int i = 0; i < 4; i++)
    tile[ty + 8 * i][tx] = W[(size_t)(k0 + ty + 8 * i) * N + n0 + tx];
  __syncthreads();
#pragma unroll
  for (int i = 0; i < 4; i++)
    WT[(size_t)(n0 + ty + 8 * i) * K + k0 + tx] = f2bf(tile[tx][ty + 8 * i]);
}

// ---------------- biasL16 = bf16(LOG2E*(sb*adj + mask) - SMAX*LOG2E) ----------------
__global__ void bias_precompute(const float* __restrict__ adj, const float* __restrict__ mask,
                                const float* __restrict__ sbp, u16* __restrict__ bias16) {
  const float sb = sbp[0];
  const float C3 = -SMAX_ * LOG2E_;
  size_t i = ((size_t)blockIdx.x * 256 + threadIdx.x) * 8;
  float4 a0 = *(const float4*)(adj + i);
  float4 a1 = *(const float4*)(adj + i + 4);
  float4 m0 = *(const float4*)(mask + i);
  float4 m1 = *(const float4*)(mask + i + 4);
  ushort4 o0, o1;
  o0.x = f2bf(fmaf(fmaf(sb, a0.x, m0.x), LOG2E_, C3));
  o0.y = f2bf(fmaf(fmaf(sb, a0.y, m0.y), LOG2E_, C3));
  o0.z = f2bf(fmaf(fmaf(sb, a0.z, m0.z), LOG2E_, C3));
  o0.w = f2bf(fmaf(fmaf(sb, a0.w, m0.w), LOG2E_, C3));
  o1.x = f2bf(fmaf(fmaf(sb, a1.x, m1.x), LOG2E_, C3));
  o1.y = f2bf(fmaf(fmaf(sb, a1.y, m1.y), LOG2E_, C3));
  o1.z = f2bf(fmaf(fmaf(sb, a1.z, m1.z), LOG2E_, C3));
  o1.w = f2bf(fmaf(fmaf(sb, a1.w, m1.w), LOG2E_, C3));
  *(ushort4*)(bias16 + i) = o0;
  *(ushort4*)(bias16 + i + 4) = o1;
}

// ---------------- layernorm [R,D] -> bf16; input fp32 (BI=0) or bf16 (BI=1) -------
template <int BI>
__global__ void ln_kernel(const void* __restrict__ xin, const float* __restrict__ g,
                          const float* __restrict__ be, u16* __restrict__ out) {
  int row = blockIdx.x;
  int t = threadIdx.x;  // 256
  float4 v;
  if (BI) {
    ushort4 uv = ((const ushort4*)((const u16*)xin + (size_t)row * Dm))[t];
    v.x = bf2f(uv.x); v.y = bf2f(uv.y); v.z = bf2f(uv.z); v.w = bf2f(uv.w);
  } else {
    v = ((const float4*)((const float*)xin + (size_t)row * Dm))[t];
  }
  float s = v.x + v.y + v.z + v.w;
  float s2 = v.x * v.x + v.y * v.y + v.z * v.z + v.w * v.w;
#pragma unroll
  for (int o = 32; o > 0; o >>= 1) { s += __shfl_down(s, o); s2 += __shfl_down(s2, o); }
  __shared__ float sm[8];
  int w = t >> 6;
  if ((t & 63) == 0) { sm[w] = s; sm[4 + w] = s2; }
  __syncthreads();
  if (t == 0) {
    float a = sm[0] + sm[1] + sm[2] + sm[3];
    float a2 = sm[4] + sm[5] + sm[6] + sm[7];
    float mu = a * (1.f / Dm);
    sm[0] = mu;
    sm[1] = rsqrtf(a2 * (1.f / Dm) - mu * mu + EPS_);
  }
  __syncthreads();
  float mu = sm[0], rstd = sm[1];
  float4 gv = ((const float4*)g)[t];
  float4 bv = ((const float4*)be)[t];
  ushort4 o4;
  o4.x = f2bf((v.x - mu) * rstd * gv.x + bv.x);
  o4.y = f2bf((v.y - mu) * rstd * gv.y + bv.y);
  o4.z = f2bf((v.z - mu) * rstd * gv.z + bv.z);
  o4.w = f2bf((v.w - mu) * rstd * gv.w + bv.w);
  ((ushort4*)(out + (size_t)row * Dm))[t] = o4;
}

// ---------------- bf16 GEMM, double-buffered + XCD m-strip ownership --------------
template <int MODE, int MI, int NI>
__global__ __launch_bounds__(256) void gemm_bt(
    const u16* __restrict__ A, const u16* __restrict__ BT,
    const float* __restrict__ bias, const void* __restrict__ res,
    void* __restrict__ Cout, u16* __restrict__ qb,
    u16* __restrict__ kb, u16* __restrict__ vb, int Ndim, int Kdim) {
  constexpr int TM = MI * 32, TN = NI * 32;
  constexpr int NS = (TM + TN) / 16;  // 16-row staging instrs per k-tile
  __shared__ u16 As[2][TM * 32];
  __shared__ u16 Bs[2][TN * 32];
  const int t = threadIdx.x;
  const int wave = t >> 6, lane = t & 63;
  const int wm = wave >> 1, wn = wave & 1;
  const int lr = lane & 15, lq = lane >> 4;
  const int flat = blockIdx.x + gridDim.x * blockIdx.y;
  constexpr int nMb = 4096 / TM;
  constexpr int mpx = nMb / 8;  // m-blocks per XCD
  const int xcd = flat & 7;
  const int p = flat >> 3;
  const int m0 = (xcd * mpx + (p % mpx)) * TM;
  const int n0 = (p / mpx) * TN;

  auto stage = [&](int kt, int bsel) {
#pragma unroll
    for (int s = wave; s < NS; s += 4) {
      if (s < TM / 16)
        g2l16(A + (size_t)(m0 + s * 16 + (lane >> 2)) * Kdim + kt + (lane & 3) * 8,
              &As[bsel][(s * 16) * 32]);
      else
        g2l16(BT + (size_t)(n0 + (s - TM / 16) * 16 + (lane >> 2)) * Kdim + kt + (lane & 3) * 8,
              &Bs[bsel][((s - TM / 16) * 16) * 32]);
    }
  };

  f32x4 acc[MI][NI];
#pragma unroll
  for (int i = 0; i < MI; i++)
#pragma unroll
    for (int j = 0; j < NI; j++) acc[i][j] = (f32x4){0.f, 0.f, 0.f, 0.f};

  stage(0, 0);
  int cur = 0;
  for (int kt = 0; kt < Kdim; kt += 32) {
    __syncthreads();  // vmcnt drain -> buf[cur] ready; protects buf[cur^1]
    if (kt + 32 < Kdim) stage(kt + 32, cur ^ 1);
    short8 af[MI], bf[NI];
#pragma unroll
    for (int i = 0; i < MI; i++)
      af[i] = *(const short8*)&As[cur][(wm * (MI * 16) + i * 16 + lr) * 32 + lq * 8];
#pragma unroll
    for (int j = 0; j < NI; j++)
      bf[j] = *(const short8*)&Bs[cur][(wn * (NI * 16) + j * 16 + lr) * 32 + lq * 8];
#pragma unroll
    for (int i = 0; i < MI; i++)
#pragma unroll
      for (int j = 0; j < NI; j++)
        acc[i][j] = __builtin_amdgcn_mfma_f32_16x16x32_bf16(af[i], bf[j], acc[i][j], 0, 0, 0);
    cur ^= 1;
  }

#pragma unroll
  for (int i = 0; i < MI; i++) {
#pragma unroll
    for (int j = 0; j < NI; j++) {
#pragma unroll
      for (int r = 0; r < 4; r++) {
        int row = m0 + wm * (MI * 16) + i * 16 + lq * 4 + r;
        int col = n0 + wn * (NI * 16) + j * 16 + lr;
        float val = acc[i][j][r] + bias[col];
        if (MODE == 0) {
          int s = col >> 10, rem = col & 1023;
          int hh = rem >> 6, dh = rem & 63;
          int bi = row >> 11, ni = row & 2047;
          if (s == 2) {
            vb[(((size_t)bi * Hh + hh) * DHh + dh) * Nn + ni] = f2bf(val);
          } else {
            u16* dst = (s == 0) ? qb : kb;
            dst[(((size_t)bi * Hh + hh) * Nn + ni) * DHh + dh] = f2bf(val);
          }
        } else if (MODE == 1) {
          size_t o = (size_t)row * Ndim + col;
          ((u16*)Cout)[o] = f2bf(val + ((const float*)res)[o]);
        } else if (MODE == 3) {
          size_t o = (size_t)row * Ndim + col;
          ((float*)Cout)[o] = val + bf2f(((const u16*)res)[o]);
        } else {
          // gelu(u) = u * sigmoid(1.5957691(u + 0.044715 u^3)); NaN-safe tails
          float u = val;
          float y2 = 1.5957691216f * fmaf(0.044715f * u, u * u, u);
          float gv = u / (1.f + __expf(-y2));
          size_t o = (size_t)row * Ndim + col;
          ((u16*)Cout)[o] = f2bf(gv);
        }
      }
    }
  }
}

// ---------------- flash attention v9: DMA-staged K/V double-buffer, 1 barrier -----
// grid (16, 32, 2): x=q-tile, y=head-batch, z=K-half.
// K/V staged via global_load_lds into 2x(8KB+8KB) LDS buffers; ONE __syncthreads
// per k-tile (its implicit vmcnt(0) drains own DMA loads; barrier makes tile
// visible block-wide — m97 pattern). Next tile's loads are issued right after the
// barrier and stay in flight across the whole compute phase.
// LDS dest is linear (g2l can't scatter) -> global SOURCE pre-swizzled
// chunk' = chunk ^ (row&7) so 128B-pitch rows read conflict-free (m173 pattern).
// Swapped QK^T (S^T in regs), ushort4 bias, packed b64 P bounce, setprio on MFMA.
// Fixed max => partials combine exactly: O=(O0+O1)/(l0+l1).
__global__ __launch_bounds__(256) void attn_kernel(
    const u16* __restrict__ q, const u16* __restrict__ k, const u16* __restrict__ vT,
    const u16* __restrict__ bias16, u16* __restrict__ pO0, u16* __restrict__ pO1,
    float* __restrict__ pl) {
  const int qt = blockIdx.x, hb = blockIdx.y, kp = blockIdx.z;
  const int hh = hb & 15, b = hb >> 4;
  const int t = threadIdx.x, wave = t >> 6, lane = t & 63;
  const int lr = lane & 15, lq = lane >> 4;
  const size_t head_off = (((size_t)b * Hh + hh) * Nn) * DHh;
  const u16* Q = q + head_off;
  const u16* K = k + head_off;
  const u16* Vt = vT + head_off;  // [DH][N]
  const int q0 = qt * 128;
  const int kbase = kp * (Nn / 2);
  u16* pO = kp ? pO1 : pO0;

  __shared__ u16 Ks[2][64 * 64];   // [k-row][dh], 128B pitch, src-swizzled
  __shared__ u16 VsT[2][64 * 64];  // [dh][n-chunk], 128B pitch, src-swizzled
  __shared__ u16 Ps[4][32 * 72];   // per-wave P bounce (72-pitch, proven)

  short8 qf[2][2];
#pragma unroll
  for (int qs = 0; qs < 2; qs++) {
    const u16* Qr = Q + (size_t)(q0 + wave * 32 + qs * 16 + lr) * DHh;
    qf[qs][0] = *(const short8*)(Qr + lq * 8);
    qf[qs][1] = *(const short8*)(Qr + 32 + lq * 8);
  }
  f32x4 o_acc[2][4];
  float l_acc[2];
#pragma unroll
  for (int qs = 0; qs < 2; qs++) {
#pragma unroll
    for (int j = 0; j < 4; j++) o_acc[qs][j] = (f32x4){0.f, 0.f, 0.f, 0.f};
    l_acc[qs] = 0.f;
  }

  // staging geometry: 16 g2l16 per tile (8 K + 8 V), 4 per wave.
  // instr s covers rows s*8..s*8+7 (1KB); lane: sub-row lane>>3, chunk lane&7.
  // source chunk pre-XORed by row&7 ( = lane>>3 since s*8 is 8-aligned).
  const int lsub = lane >> 3;
  const int xch = ((lane & 7) ^ lsub) * 8;  // swizzled element offset in row

  auto stage = [&](int kt, int bsel) {
#pragma unroll
    for (int i = 0; i < 4; i++) {
      const int s = wave + i * 4;
      if (s < 8)
        g2l16(K + (size_t)(kt + s * 8 + lsub) * DHh + xch, &Ks[bsel][s * 512]);
      else
        g2l16(Vt + (size_t)((s - 8) * 8 + lsub) * Nn + kt + xch,
              &VsT[bsel][(s - 8) * 512]);
    }
  };

  const int rsw = ((lr >> 2) & 3) << 4;  // Ps read swizzle (v7)
  const int kx = lr & 7;                 // K/V read row-XOR key
  // bias row for this thread's q (q = q0 + wave*32 + qs*16 + lr)
  const u16* bp = bias16 + ((size_t)b * Nn + q0 + wave * 32 + lr) * Nn;
  const float C1 = SCALE_ * LOG2E_;
  const int kend = kbase + Nn / 2;

  ushort4 bw[2][4];  // [qs][ns] = bias at (q, k = kt + ns*16 + lq*4 .. +3)
#pragma unroll
  for (int qs = 0; qs < 2; qs++)
#pragma unroll
    for (int ns = 0; ns < 4; ns++)
      bw[qs][ns] = *(const ushort4*)(bp + (size_t)qs * 16 * Nn + kbase + ns * 16 + lq * 4);

  stage(kbase, 0);
  int cur = 0;
  for (int kt = kbase; kt < kend; kt += 64) {
    __syncthreads();  // implicit vmcnt(0)+barrier: buf[cur] complete block-wide
    if (kt + 64 < kend) stage(kt + 64, cur ^ 1);  // in flight across compute
    const u16* Kc = Ks[cur];
    const u16* Vc = VsT[cur];

    short8 kf[4][2];
#pragma unroll
    for (int ns = 0; ns < 4; ns++) {
      int R = ns * 16 + lr;
      kf[ns][0] = *(const short8*)&Kc[R * 64 + ((lq ^ kx) * 8)];
      kf[ns][1] = *(const short8*)&Kc[R * 64 + (((4 + lq) ^ kx) * 8)];
    }
    // S^T = mfma(K-frag as A, Q-frag as B): D[m=k][n=q]
    f32x4 s0[4], s1[4];
    __builtin_amdgcn_s_setprio(1);
#pragma unroll
    for (int ns = 0; ns < 4; ns++) {
      f32x4 z = (f32x4){0.f, 0.f, 0.f, 0.f};
      s0[ns] = __builtin_amdgcn_mfma_f32_16x16x32_bf16(kf[ns][0], qf[0][0], z, 0, 0, 0);
      s0[ns] = __builtin_amdgcn_mfma_f32_16x16x32_bf16(kf[ns][1], qf[0][1], s0[ns], 0, 0, 0);
      s1[ns] = __builtin_amdgcn_mfma_f32_16x16x32_bf16(kf[ns][0], qf[1][0], z, 0, 0, 0);
      s1[ns] = __builtin_amdgcn_mfma_f32_16x16x32_bf16(kf[ns][1], qf[1][1], s1[ns], 0, 0, 0);
    }
    __builtin_amdgcn_s_setprio(0);

    float p0[4][4], p1[4][4];
#pragma unroll
    for (int ns = 0; ns < 4; ns++) {
      p0[ns][0] = exp2f(fmaf(s0[ns][0], C1, bf2f(bw[0][ns].x)));
      p0[ns][1] = exp2f(fmaf(s0[ns][1], C1, bf2f(bw[0][ns].y)));
      p0[ns][2] = exp2f(fmaf(s0[ns][2], C1, bf2f(bw[0][ns].z)));
      p0[ns][3] = exp2f(fmaf(s0[ns][3], C1, bf2f(bw[0][ns].w)));
      p1[ns][0] = exp2f(fmaf(s1[ns][0], C1, bf2f(bw[1][ns].x)));
      p1[ns][1] = exp2f(fmaf(s1[ns][1], C1, bf2f(bw[1][ns].y)));
      p1[ns][2] = exp2f(fmaf(s1[ns][2], C1, bf2f(bw[1][ns].z)));
      p1[ns][3] = exp2f(fmaf(s1[ns][3], C1, bf2f(bw[1][ns].w)));
      l_acc[0] += (p0[ns][0] + p0[ns][1]) + (p0[ns][2] + p0[ns][3]);
      l_acc[1] += (p1[ns][0] + p1[ns][1]) + (p1[ns][2] + p1[ns][3]);
    }
    if (kt + 64 < kend) {  // prefetch next tile's bias during the rest of compute
#pragma unroll
      for (int qs = 0; qs < 2; qs++)
#pragma unroll
        for (int ns = 0; ns < 4; ns++)
          bw[qs][ns] = *(const ushort4*)(bp + (size_t)qs * 16 * Nn + kt + 64 + ns * 16 + lq * 4);
    }
    // P bounce: row q = qs*16+lr, true cols ns*16 + lq*4 .. +3 (b64 packed)
#pragma unroll
    for (int ns = 0; ns < 4; ns++) {
      int sc = ((ns ^ ((lr >> 2) & 3)) << 4) + lq * 4;
      uint2 w0, w1;
      w0.x = pk2(p0[ns][0], p0[ns][1]); w0.y = pk2(p0[ns][2], p0[ns][3]);
      w1.x = pk2(p1[ns][0], p1[ns][1]); w1.y = pk2(p1[ns][2], p1[ns][3]);
      *(uint2*)&Ps[wave][lr * 72 + sc] = w0;
      *(uint2*)&Ps[wave][(16 + lr) * 72 + sc] = w1;
    }
    short8 pf[2][2];
#pragma unroll
    for (int qs = 0; qs < 2; qs++) {
      pf[qs][0] = *(const short8*)&Ps[wave][(qs * 16 + lr) * 72 + ((lq * 8) ^ rsw)];
      pf[qs][1] = *(const short8*)&Ps[wave][(qs * 16 + lr) * 72 + ((32 + lq * 8) ^ rsw)];
    }
#pragma unroll
    for (int j = 0; j < 4; j++) {
      int R = j * 16 + lr;
      short8 vf0 = *(const short8*)&Vc[R * 64 + ((lq ^ kx) * 8)];
      short8 vf1 = *(const short8*)&Vc[R * 64 + (((4 + lq) ^ kx) * 8)];
      __builtin_amdgcn_s_setprio(1);
      o_acc[0][j] = __builtin_amdgcn_mfma_f32_16x16x32_bf16(pf[0][0], vf0, o_acc[0][j], 0, 0, 0);
      o_acc[0][j] = __builtin_amdgcn_mfma_f32_16x16x32_bf16(pf[0][1], vf1, o_acc[0][j], 0, 0, 0);
      o_acc[1][j] = __builtin_amdgcn_mfma_f32_16x16x32_bf16(pf[1][0], vf0, o_acc[1][j], 0, 0, 0);
      o_acc[1][j] = __builtin_amdgcn_mfma_f32_16x16x32_bf16(pf[1][1], vf1, o_acc[1][j], 0, 0, 0);
      __builtin_amdgcn_s_setprio(0);
    }
    cur ^= 1;
  }
  // epilogue: l per thread covers q=lr only -> reduce across the 4 lq groups
#pragma unroll
  for (int qs = 0; qs < 2; qs++) {
    float l = l_acc[qs];
    l += __shfl_xor(l, 16);
    l += __shfl_xor(l, 32);
    if (lane < 16)
      pl[((size_t)(kp * Bb + b) * Hh + hh) * Nn + q0 + wave * 32 + qs * 16 + lr] = l;
#pragma unroll
    for (int r = 0; r < 4; r++) {
      int qrow = q0 + wave * 32 + qs * 16 + lq * 4 + r;
#pragma unroll
      for (int j = 0; j < 4; j++) {
        pO[((size_t)(b * Nn + qrow)) * Dm + hh * DHh + j * 16 + lr] =
            f2bf(o_acc[qs][j][r]);
      }
    }
  }
}

// ---------------- combine K-split partials: ao = (O0+O1)/(l0+l1) ----------------
__global__ void attn_combine(const u16* __restrict__ pO0, const u16* __restrict__ pO1,
                             const float* __restrict__ pl, u16* __restrict__ ao) {
  int row = blockIdx.x;   // 0..4095
  int t = threadIdx.x;    // 256
  int col = t * 4;
  int b = row >> 11, n = row & 2047, hh = col >> 6;
  size_t li = ((size_t)b * Hh + hh) * Nn + n;
  float inv = 1.f / (pl[li] + pl[(size_t)Bb * Hh * Nn + li]);
  ushort4 a0 = *(const ushort4*)(pO0 + (size_t)row * Dm + col);
  ushort4 a1 = *(const ushort4*)(pO1 + (size_t)row * Dm + col);
  ushort4 o;
  o.x = f2bf((bf2f(a0.x) + bf2f(a1.x)) * inv);
  o.y = f2bf((bf2f(a0.y) + bf2f(a1.y)) * inv);
  o.z = f2bf((bf2f(a0.z) + bf2f(a1.z)) * inv);
  o.w = f2bf((bf2f(a0.w) + bf2f(a1.w)) * inv);
  *(ushort4*)(ao + (size_t)row * Dm + col) = o;
}

extern "C" void kernel_launch(void* const* d_in, const int* in_sizes, int n_in,
                              void* d_out, int out_size, void* d_ws, size_t ws_size,
                              hipStream_t stream) {
  const float* x     = (const float*)d_in[0];
  const float* adj   = (const float*)d_in[1];
  const float* amask = (const float*)d_in[2];
  const float* qkv_w = (const float*)d_in[3];
  const float* qkv_b = (const float*)d_in[4];
  const float* out_w = (const float*)d_in[5];
  const float* out_b = (const float*)d_in[6];
  const float* ln1_g = (const float*)d_in[7];
  const float* ln1_b = (const float*)d_in[8];
  const float* ln2_g = (const float*)d_in[9];
  const float* ln2_b = (const float*)d_in[10];
  const float* ff1_w = (const float*)d_in[11];
  const float* ff1_b = (const float*)d_in[12];
  const float* ff2_w = (const float*)d_in[13];
  const float* ff2_b = (const float*)d_in[14];
  const float* sbias = (const float*)d_in[15];

  char* w = (char*)d_ws;
  const size_t MB = 1024 * 1024;
  u16* h      = (u16*)(w);             // 8 MB
  u16* qb     = (u16*)(w + 8 * MB);    // 8 MB
  u16* kb     = (u16*)(w + 16 * MB);   // 8 MB
  u16* vb     = (u16*)(w + 24 * MB);   // 8 MB ([B,H,DH,N])
  u16* ao     = (u16*)(w + 32 * MB);   // 8 MB
  float* pl   = (float*)(w + 40 * MB); // 0.5 MB (dead before x1 write)
  u16* x1     = (u16*)(w + 40 * MB);   // 8 MB (bf16, written after combine)
  u16* pO0    = (u16*)(w + 48 * MB);   // 8 MB
  u16* pO1    = h;                     // 8 MB (h dead during attn)
  u16* qkvT   = (u16*)(w + 56 * MB);   // 6 MB
  u16* outT   = (u16*)(w + 62 * MB);   // 2 MB
  u16* ff1T   = (u16*)(w + 64 * MB);   // 8 MB
  u16* ff2T   = (u16*)(w + 72 * MB);   // 8 MB
  u16* bias16 = (u16*)(w + 80 * MB);   // 16.8 MB
  u16* ffo    = qb;                    // 32 MB alias over qb..ao (dead after out-proj)

  transpose_all<<<dim3(12288), dim3(32, 8), 0, stream>>>(
      qkv_w, out_w, ff1_w, ff2_w, qkvT, outT, ff1T, ff2T);

  bias_precompute<<<dim3((Bb * Nn * Nn) / (8 * 256)), dim3(256), 0, stream>>>(adj, amask, sbias, bias16);

  ln_kernel<0><<<dim3(Rr), dim3(256), 0, stream>>>(x, ln1_g, ln1_b, h);

  gemm_bt<0, 4, 4><<<dim3(3072 / 128, 4096 / 128), dim3(256), 0, stream>>>(
      h, qkvT, qkv_b, nullptr, nullptr, qb, kb, vb, 3072, 1024);

  attn_kernel<<<dim3(16, 32, 2), dim3(256), 0, stream>>>(qb, kb, vb, bias16, pO0, pO1, pl);

  attn_combine<<<dim3(Rr), dim3(256), 0, stream>>>(pO0, pO1, pl, ao);

  gemm_bt<1, 4, 2><<<dim3(1024 / 64, 4096 / 128), dim3(256), 0, stream>>>(
      ao, outT, out_b, x, (void*)x1, nullptr, nullptr, nullptr, 1024, 1024);

  ln_kernel<1><<<dim3(Rr), dim3(256), 0, stream>>>(x1, ln2_g, ln2_b, h);

  gemm_bt<2, 4, 4><<<dim3(4096 / 128, 4096 / 128), dim3(256), 0, stream>>>(
      h, ff1T, ff1_b, nullptr, (void*)ffo, nullptr, nullptr, nullptr, 4096, 1024);

  gemm_bt<3, 4, 2><<<dim3(1024 / 64, 4096 / 128), dim3(256), 0, stream>>>(
      ffo, ff2T, ff2_b, x1, d_out, nullptr, nullptr, nullptr, 1024, 4096);
}